// Round 19
// baseline (342.768 us; speedup 1.0000x reference)
//
#include <hip/hip_runtime.h>
#include <stdint.h>

#define Bb 8
#define Cc 2048
#define Ee 1024

typedef unsigned short u16;
typedef __attribute__((ext_vector_type(8))) short short8;
typedef __attribute__((ext_vector_type(16))) float f32x16;

__device__ __forceinline__ u16 f2bf(float f){
    unsigned u = __builtin_bit_cast(unsigned, f);
    return (u16)((u + 0x7fffu + ((u >> 16) & 1u)) >> 16);   // RNE, finite inputs
}
__device__ __forceinline__ void gld16(const void* g, void* l){
    __builtin_amdgcn_global_load_lds(
        (const __attribute__((address_space(1))) unsigned int*)g,
        (__attribute__((address_space(3))) unsigned int*)l,
        16, 0, 0);
}
#define MFMA32(a,b,c) __builtin_amdgcn_mfma_f32_32x32x16_bf16((a),(b),(c),0,0,0)
#define SBAR()  __builtin_amdgcn_s_barrier()
#define SCHED0() __builtin_amdgcn_sched_barrier(0)
#define LGKM6() asm volatile("s_waitcnt lgkmcnt(6)" ::: "memory")
#define LGKM0() asm volatile("s_waitcnt lgkmcnt(0)" ::: "memory")
#define VMCNT0() asm volatile("s_waitcnt vmcnt(0)" ::: "memory")

// ---------------- merged prep (vectorized): x cast+transpose AND 3 weight casts ----------------
__global__ __launch_bounds__(256) void k_prep(const float* __restrict__ x,
                                              u16* __restrict__ xb, u16* __restrict__ xbT,
                                              const float* __restrict__ fw, u16* __restrict__ fwb,
                                              const float* __restrict__ vw, u16* __restrict__ vwb,
                                              const float* __restrict__ aw, u16* __restrict__ awb){
    __shared__ float tile[64][68];              // 68: 16B-aligned rows, bank-rotated
    const int blk = blockIdx.x;
    const int tid = threadIdx.x;
    if (blk < 4096){
        // x: [b][C][E] fp32 -> xb bf16 + xbT [b][E][C] bf16; 64x64 tile
        const int cx = blk & 15;                // E/64
        const int rest = blk >> 4;
        const int cy = rest & 31;               // C/64
        const int b  = rest >> 5;
        const float* src = x + (long)b * Cc * Ee;
        u16* xbp  = xb  + (long)b * Cc * Ee;
        u16* xbTp = xbT + (long)b * Cc * Ee;
        const int c0 = cx * 64;
        const int r0 = cy * 64;
        const int tx = tid & 15;                // float4 col (16 x 4 = 64 cols)
        const int ty = tid >> 4;                // 0..15
        #pragma unroll
        for (int p = 0; p < 4; ++p){
            const int r = ty + p * 16;
            float4 v = *(const float4*)&src[(long)(r0 + r) * Ee + c0 + tx * 4];
            *(float4*)&tile[r][tx * 4] = v;
            ushort4 o = make_ushort4(f2bf(v.x), f2bf(v.y), f2bf(v.z), f2bf(v.w));
            *(ushort4*)&xbp[(long)(r0 + r) * Ee + c0 + tx * 4] = o;
        }
        __syncthreads();
        const int oc = tid >> 2;                // out-row (E-col), 0..63
        const int cq = tid & 3;
        #pragma unroll
        for (int s = 0; s < 4; ++s){
            const int rr = cq * 4 + s * 16;     // out-col base (C-row)
            ushort4 o = make_ushort4(f2bf(tile[rr    ][oc]), f2bf(tile[rr + 1][oc]),
                                     f2bf(tile[rr + 2][oc]), f2bf(tile[rr + 3][oc]));
            *(ushort4*)&xbTp[(long)(c0 + oc) * Cc + r0 + rr] = o;
        }
    } else {
        const long n0 = (long)Ee * Ee / 4, n1 = n0, n2 = (long)Cc * Cc / 4;
        long i = (long)(blk - 4096) * 256 + tid;
        const long stride = 2048L * 256;
        const long tot = n0 + n1 + n2;
        for (; i < tot; i += stride){
            const float* s; u16* d; long k;
            if (i < n0)          { s = fw; d = fwb; k = i; }
            else if (i < n0 + n1){ s = vw; d = vwb; k = i - n0; }
            else                 { s = aw; d = awb; k = i - n0 - n1; }
            float4 f = ((const float4*)s)[k];
            ((ushort4*)d)[k] = make_ushort4(f2bf(f.x), f2bf(f.y), f2bf(f.z), f2bf(f.w));
        }
    }
}

// ====== 256x256 NT GEMM — 32x32x16 MFMA shape (2495 TF ceiling vs 2075; half the issues) ======
// C[m,n] = scale*sum_k A[m,k]B[n,k]; A:[M,K], B:[N,K] bf16 row-major.
// 512 thr = 8 waves (2M x 4N); per-wave 128x64 = 4mt x 2nt tiles of 32x32; BK=64 = 4 ksteps.
// LDS layout/staging identical to R14 (64x64-unit gld16, chunk ^ (row&7) swizzle).
// A/B frag: lane row = lane&31, k-chunk = lane>>5 (8 bf16); C/D: col=lane&31,
// row=(reg&3)+8*(reg>>2)+4*(lane>>5) [HW-verified m74/m101].
// K-loop: per kstep 6 reads (4A+2B); ping-pong frag sets; lgkm(6) waits; 1 barrier/tile.
// EPI: 0 plain (+bias) | 1 exp+row-partials | 2 div-by-rowsum fp32
//      | 3 split-yv: tileN<1024 -> y[c][f]+bias; else vxT[f-1024][c] transposed +bias2.
template<int BIAS_MODE, int OUT_F32, int EPI>
__global__ __launch_bounds__(512, 2)
void k_gemm256(const u16* __restrict__ A, const u16* __restrict__ Bm,
               void* __restrict__ Cout, const float* __restrict__ bias,
               const float* __restrict__ bias2, float* __restrict__ extra,
               int N, int K, long sA, long sB, long sC, float scale)
{
    __shared__ __attribute__((aligned(16))) char smem[131072];

    // ---- bijective XCD swizzle (nwg % 8 == 0 for all launches here)
    const int gx = gridDim.x, gy = gridDim.y;
    const int nwg = gx * gy * gridDim.z;
    const int lin = blockIdx.x + gx * (blockIdx.y + gy * blockIdx.z);
    const int swz = (lin & 7) * (nwg >> 3) + (lin >> 3);
    const int bx = swz % gx;
    const int tmp = swz / gx;
    const int by = tmp % gy;
    const int bz = tmp / gy;

    const u16* Ap  = A  + (long)bz * sA;
    const u16* Bp  = Bm + (long)bz * sB;
    u16*   Cm = (u16*)Cout + (long)bz * sC;
    float* Cf = (float*)Cout + (long)bz * sC;

    const int tid  = threadIdx.x;
    const int lane = tid & 63;
    const int wave = tid >> 6;
    const int wr = wave >> 2;          // 0..1  (M half)
    const int wc = wave & 3;           // 0..3  (N quarter)
    const int tileM = bx * 256;
    const int tileN = by * 256;

    // ---- staging constants: unit = 64 rows x 64 cols (8KiB) = 1 gld16/thread
    const int srow   = tid >> 3;
    const int schunk = (tid & 7) ^ (srow & 7);   // pre-swizzled 16B chunk
    const u16* Ag = Ap + (long)(tileM + srow) * K + schunk * 8;
    const u16* Bg = Bp + (long)(tileN + srow) * K + schunk * 8;
    const long uK = (long)64 * K;
    const int  ldst = tid * 16;

    // ---- ds_read constants (32x32 frag: row = lane&31, k-half = lane>>5)
    const int l31 = lane & 31;
    const int hi  = lane >> 5;
    const int sw32 = l31 & 7;
    const int a32 = (wr*128 + l31) * 128;                // + mt*4096 + cs(ks)
    const int b32 = 32768 + (wc*64 + l31) * 128;         // + nt*4096 + cs(ks)
    #define CSK(ks) ((((2*(ks)) + hi) ^ sw32) << 4)

    f32x16 acc[8];                                       // [mt*2+nt]
    #pragma unroll
    for (int t8 = 0; t8 < 8; ++t8)
        #pragma unroll
        for (int i = 0; i < 16; ++i)
            acc[t8][i] = 0.f;

    char* sm = smem;
    #pragma unroll
    for (int u = 0; u < 4; ++u) gld16(Bg + u*uK, sm + 32768 + u*8192 + ldst);
    #pragma unroll
    for (int u = 0; u < 4; ++u) gld16(Ag + u*uK, sm + u*8192 + ldst);
    __syncthreads();

    const int NT = K >> 6;
    short8 aP[4], bP[2], aQ[4], bQ[2];

    for (int t = 0; t < NT; ++t){
        const bool pref = (t + 1) < NT;
        char* cbuf = sm + ((t & 1) << 16);
        char* nbuf = sm + (((t + 1) & 1) << 16);
        const u16* Agt = Ag + (long)(t + 1) * 64;
        const u16* Bgt = Bg + (long)(t + 1) * 64;

        // ---- ks0 + ks1 reads (12 b128)
        #pragma unroll
        for (int mt = 0; mt < 4; ++mt) aP[mt] = *(const short8*)(cbuf + a32 + mt*4096 + CSK(0));
        #pragma unroll
        for (int nt = 0; nt < 2; ++nt) bP[nt] = *(const short8*)(cbuf + b32 + nt*4096 + CSK(0));
        #pragma unroll
        for (int mt = 0; mt < 4; ++mt) aQ[mt] = *(const short8*)(cbuf + a32 + mt*4096 + CSK(1));
        #pragma unroll
        for (int nt = 0; nt < 2; ++nt) bQ[nt] = *(const short8*)(cbuf + b32 + nt*4096 + CSK(1));

        // ---- staging burst (vmcnt only; lands under compute)
        if (pref){
            gld16(Agt + 0*uK, nbuf + 0*8192 + ldst);
            gld16(Agt + 1*uK, nbuf + 1*8192 + ldst);
            gld16(Agt + 2*uK, nbuf + 2*8192 + ldst);
            gld16(Agt + 3*uK, nbuf + 3*8192 + ldst);
            gld16(Bgt + 0*uK, nbuf + 32768 + 0*8192 + ldst);
            gld16(Bgt + 1*uK, nbuf + 32768 + 1*8192 + ldst);
            gld16(Bgt + 2*uK, nbuf + 32768 + 2*8192 + ldst);
            gld16(Bgt + 3*uK, nbuf + 32768 + 3*8192 + ldst);
        }

        LGKM6(); SCHED0();                       // ks0 frags ready
        #pragma unroll
        for (int mt = 0; mt < 4; ++mt)
            #pragma unroll
            for (int nt = 0; nt < 2; ++nt)
                acc[mt*2+nt] = MFMA32(aP[mt], bP[nt], acc[mt*2+nt]);

        // ---- ks2 reads into aP,bP
        #pragma unroll
        for (int mt = 0; mt < 4; ++mt) aP[mt] = *(const short8*)(cbuf + a32 + mt*4096 + CSK(2));
        #pragma unroll
        for (int nt = 0; nt < 2; ++nt) bP[nt] = *(const short8*)(cbuf + b32 + nt*4096 + CSK(2));
        LGKM6(); SCHED0();                       // ks1 ready
        #pragma unroll
        for (int mt = 0; mt < 4; ++mt)
            #pragma unroll
            for (int nt = 0; nt < 2; ++nt)
                acc[mt*2+nt] = MFMA32(aQ[mt], bQ[nt], acc[mt*2+nt]);

        // ---- ks3 reads into aQ,bQ
        #pragma unroll
        for (int mt = 0; mt < 4; ++mt) aQ[mt] = *(const short8*)(cbuf + a32 + mt*4096 + CSK(3));
        #pragma unroll
        for (int nt = 0; nt < 2; ++nt) bQ[nt] = *(const short8*)(cbuf + b32 + nt*4096 + CSK(3));
        LGKM6(); SCHED0();                       // ks2 ready
        #pragma unroll
        for (int mt = 0; mt < 4; ++mt)
            #pragma unroll
            for (int nt = 0; nt < 2; ++nt)
                acc[mt*2+nt] = MFMA32(aP[mt], bP[nt], acc[mt*2+nt]);

        LGKM0(); SCHED0();                       // ks3 ready
        #pragma unroll
        for (int mt = 0; mt < 4; ++mt)
            #pragma unroll
            for (int nt = 0; nt < 2; ++nt)
                acc[mt*2+nt] = MFMA32(aQ[mt], bQ[nt], acc[mt*2+nt]);

        VMCNT0(); SBAR(); SCHED0();
    }
    #undef CSK

    // ---- epilogue: C/D layout col=lane&31, row=(reg&3)+8*(reg>>2)+4*(lane>>5)
    const int rbase = tileM + wr*128 + 4*hi;     // + mt*32 + 8*r4 + j
    const int cbase = tileN + wc*64 + l31;       // + nt*32

    if (EPI == 0){
        #pragma unroll
        for (int mt = 0; mt < 4; ++mt)
            #pragma unroll
            for (int nt = 0; nt < 2; ++nt){
                const int c = cbase + nt*32;
                f32x16 v = acc[mt*2+nt];
                #pragma unroll
                for (int r4 = 0; r4 < 4; ++r4)
                    #pragma unroll
                    for (int j = 0; j < 4; ++j){
                        const int row = rbase + mt*32 + 8*r4 + j;
                        float val = v[r4*4+j] * scale;
                        if (BIAS_MODE == 1) val += bias[c];
                        if (BIAS_MODE == 2) val += bias[row];
                        if (OUT_F32) Cf[(long)row * N + c] = val;
                        else         Cm[(long)row * N + c] = f2bf(val);
                    }
            }
    } else if (EPI == 1){
        // store exp(s*scale) bf16; per-row partial sums -> extra[bz][row][by]
        float* lsum = (float*)smem;              // [256 rows][4 wc]
        #pragma unroll
        for (int mt = 0; mt < 4; ++mt)
            #pragma unroll
            for (int r4 = 0; r4 < 4; ++r4)
                #pragma unroll
                for (int j = 0; j < 4; ++j){
                    const int row = rbase + mt*32 + 8*r4 + j;
                    float e0 = __expf(acc[mt*2+0][r4*4+j] * scale);
                    float e1 = __expf(acc[mt*2+1][r4*4+j] * scale);
                    Cm[(long)row * N + cbase]      = f2bf(e0);
                    Cm[(long)row * N + cbase + 32] = f2bf(e1);
                    float rp = e0 + e1;
                    rp += __shfl_xor(rp, 1);
                    rp += __shfl_xor(rp, 2);
                    rp += __shfl_xor(rp, 4);
                    rp += __shfl_xor(rp, 8);
                    rp += __shfl_xor(rp, 16);
                    if (l31 == 0)
                        lsum[(wr*128 + 4*hi + mt*32 + 8*r4 + j)*4 + wc] = rp;
                }
        __syncthreads();
        if (tid < 256){
            float4 v4 = ((const float4*)lsum)[tid];
            extra[((long)bz*Cc + tileM + tid)*8 + by] = v4.x + v4.y + v4.z + v4.w;
        }
    } else if (EPI == 2){
        // divide by row sum (8 partials), fp32 out
        #pragma unroll
        for (int mt = 0; mt < 4; ++mt)
            #pragma unroll
            for (int r4 = 0; r4 < 4; ++r4)
                #pragma unroll
                for (int j = 0; j < 4; ++j){
                    const int row = rbase + mt*32 + 8*r4 + j;
                    const float4* pr = (const float4*)(extra + ((long)bz*Cc + row)*8);
                    float4 pa = pr[0], pb = pr[1];
                    float Ssum = pa.x+pa.y+pa.z+pa.w + pb.x+pb.y+pb.z+pb.w;
                    const float inv = 1.f / Ssum;
                    Cf[(long)row * N + cbase]      = acc[mt*2+0][r4*4+j] * inv;
                    Cf[(long)row * N + cbase + 32] = acc[mt*2+1][r4*4+j] * inv;
                }
    } else {
        // EPI == 3: yv split. tileN<1024 -> y half (ld=Ee, +bias[c]);
        //           else vxT[f'][k] transposed (ld=Cc, +bias2[f']), f'=c-1024.
        if (tileN < 1024){
            #pragma unroll
            for (int mt = 0; mt < 4; ++mt)
                #pragma unroll
                for (int nt = 0; nt < 2; ++nt){
                    const int c = cbase + nt*32;
                    f32x16 v = acc[mt*2+nt];
                    #pragma unroll
                    for (int r4 = 0; r4 < 4; ++r4)
                        #pragma unroll
                        for (int j = 0; j < 4; ++j){
                            const int row = rbase + mt*32 + 8*r4 + j;
                            Cm[(long)row * Ee + c] = f2bf(v[r4*4+j] + bias[c]);
                        }
                }
        } else {
            u16* vxp = (u16*)extra + (long)bz * sC;   // vxT base for this batch
            #pragma unroll
            for (int mt = 0; mt < 4; ++mt)
                #pragma unroll
                for (int nt = 0; nt < 2; ++nt){
                    const int c = cbase + nt*32;
                    const float b2 = bias2[c - 1024];
                    f32x16 v = acc[mt*2+nt];
                    #pragma unroll
                    for (int r4 = 0; r4 < 4; ++r4){
                        const int rowg = rbase + mt*32 + 8*r4;   // 4 contiguous rows
                        ushort4 o = make_ushort4(f2bf(v[r4*4+0]+b2), f2bf(v[r4*4+1]+b2),
                                                 f2bf(v[r4*4+2]+b2), f2bf(v[r4*4+3]+b2));
                        *(ushort4*)&vxp[(long)(c - 1024) * Cc + rowg] = o;
                    }
                }
        }
    }
}

extern "C" void kernel_launch(void* const* d_in, const int* in_sizes, int n_in,
                              void* d_out, int out_size, void* d_ws, size_t ws_size,
                              hipStream_t stream)
{
    const float* x     = (const float*)d_in[0];
    const float* fc_w  = (const float*)d_in[1];
    const float* fc_b  = (const float*)d_in[2];
    const float* altw  = (const float*)d_in[3];
    const float* altb  = (const float*)d_in[4];
    const float* vfc_w = (const float*)d_in[5];
    const float* vfc_b = (const float*)d_in[6];
    float* out = (float*)d_out;   // reference output is fp32

    char* ws = (char*)d_ws;
    const size_t nBCE = (size_t)Bb * Cc * Ee;            // 16,777,216 elements
    u16* xb   = (u16*)(ws);                              // [B][C][E]
    u16* xbT  = (u16*)(ws + 2 * nBCE);                   // [B][E][C]
    u16* P    = (u16*)(ws);                              // [B][C][C] (aliases xb+xbT; written only
                                                         //   after all xb/xbT readers complete)
    u16* y    = (u16*)(ws + 4 * nBCE);                   // [B][C][E]
    u16* z    = (u16*)(ws + 6 * nBCE);                   // [B][C][E]   z[b][k][e] = yx[b,e,k]
    u16* vxT  = (u16*)(ws + 8 * nBCE);                   // [B][E][C]   vxT[b][f][k] = vx[b,k,f]
    u16* fcwb = (u16*)(ws + 10 * nBCE);                  // [E][E]  } contiguous => 2048x1024
    u16* vfwb = fcwb + (size_t)Ee * Ee;                  // [E][E]  } concatenated weight wcat
    u16* awb  = vfwb + (size_t)Ee * Ee;                  // [C][C]
    float* rpart = (float*)(ws + 10 * nBCE + 2*((size_t)Ee*Ee*2 + (size_t)Cc*Cc));  // after weights

    const long sBCE = (long)Cc * Ee;
    const long sBCC = (long)Cc * Cc;
    dim3 blk(512);

    // 1) merged prep: x cast(+transpose, vectorized) + 3 weight casts
    k_prep<<<6144, 256, 0, stream>>>(x, xb, xbT, fc_w, fcwb, vfc_w, vfwb, altw, awb);

    // 2) z[b][k][e] = sum_c altw[k,c] xT[e,c] + alt_b[k]      M=C,N=E,K=C (bias row)
    k_gemm256<2, 0, 0><<<dim3(8, 4, Bb), blk, 0, stream>>>(
        awb, xbT, z, altb, nullptr, nullptr, Ee, Cc, 0, sBCE, sBCE, 1.f);

    // 3) yv combined: A=xb, B=wcat(2048x1024). f<1024 -> y[c][f]+fc_b; f>=1024 ->
    //    vxT[f-1024][c]+vfc_b (transposed store).  M=C, N=2048, K=E.
    k_gemm256<0, 0, 3><<<dim3(8, 8, Bb), blk, 0, stream>>>(
        xb, fcwb, y, fc_b, vfc_b, (float*)vxT, 2048, Ee, sBCE, 0, sBCE, 1.f);

    // 4) Pexp[b][c][k] = exp(scale * sum_e y[c,e] z[k,e]); row partials -> rpart
    k_gemm256<0, 0, 1><<<dim3(8, 8, Bb), blk, 0, stream>>>(
        y, z, P, nullptr, nullptr, rpart, Cc, Ee, sBCE, sBCE, sBCC, 0.022097086912079608f);

    // 5) out[b][c][e] = (sum_k Pexp[c,k] vxT[e,k]) / rowsum[c] -> fp32
    k_gemm256<0, 1, 2><<<dim3(8, 4, Bb), blk, 0, stream>>>(
        P, vxT, out, nullptr, nullptr, rpart, Ee, Cc, sBCC, sBCE, sBCE, 1.f);
}

// Round 20
// 300.769 us; speedup vs baseline: 1.1396x; 1.1396x over previous
//
#include <hip/hip_runtime.h>
#include <stdint.h>

#define Bb 8
#define Cc 2048
#define Ee 1024

typedef unsigned short u16;
typedef __attribute__((ext_vector_type(8))) short short8;
typedef __attribute__((ext_vector_type(4))) float f32x4;

__device__ __forceinline__ u16 f2bf(float f){
    unsigned u = __builtin_bit_cast(unsigned, f);
    return (u16)((u + 0x7fffu + ((u >> 16) & 1u)) >> 16);   // RNE, finite inputs
}
__device__ __forceinline__ void gld16(const void* g, void* l){
    __builtin_amdgcn_global_load_lds(
        (const __attribute__((address_space(1))) unsigned int*)g,
        (__attribute__((address_space(3))) unsigned int*)l,
        16, 0, 0);
}
#define MFMA(a,b,c) __builtin_amdgcn_mfma_f32_16x16x32_bf16((a),(b),(c),0,0,0)
#define SBAR()  __builtin_amdgcn_s_barrier()
#define SCHED0() __builtin_amdgcn_sched_barrier(0)
#define LGKM8() asm volatile("s_waitcnt lgkmcnt(8)" ::: "memory")
#define LGKM4() asm volatile("s_waitcnt lgkmcnt(4)" ::: "memory")
#define LGKM0() asm volatile("s_waitcnt lgkmcnt(0)" ::: "memory")
#define VMCNT0() asm volatile("s_waitcnt vmcnt(0)" ::: "memory")

// ---------------- merged prep (vectorized): x cast+transpose AND 3 weight casts ----------------
__global__ __launch_bounds__(256) void k_prep(const float* __restrict__ x,
                                              u16* __restrict__ xb, u16* __restrict__ xbT,
                                              const float* __restrict__ fw, u16* __restrict__ fwb,
                                              const float* __restrict__ vw, u16* __restrict__ vwb,
                                              const float* __restrict__ aw, u16* __restrict__ awb){
    __shared__ float tile[64][68];              // 68: 16B-aligned rows, bank-rotated
    const int blk = blockIdx.x;
    const int tid = threadIdx.x;
    if (blk < 4096){
        // x: [b][C][E] fp32 -> xb bf16 + xbT [b][E][C] bf16; 64x64 tile
        const int cx = blk & 15;                // E/64
        const int rest = blk >> 4;
        const int cy = rest & 31;               // C/64
        const int b  = rest >> 5;
        const float* src = x + (long)b * Cc * Ee;
        u16* xbp  = xb  + (long)b * Cc * Ee;
        u16* xbTp = xbT + (long)b * Cc * Ee;
        const int c0 = cx * 64;
        const int r0 = cy * 64;
        const int tx = tid & 15;                // float4 col (16 x 4 = 64 cols)
        const int ty = tid >> 4;                // 0..15
        #pragma unroll
        for (int p = 0; p < 4; ++p){
            const int r = ty + p * 16;
            float4 v = *(const float4*)&src[(long)(r0 + r) * Ee + c0 + tx * 4];
            *(float4*)&tile[r][tx * 4] = v;
            ushort4 o = make_ushort4(f2bf(v.x), f2bf(v.y), f2bf(v.z), f2bf(v.w));
            *(ushort4*)&xbp[(long)(r0 + r) * Ee + c0 + tx * 4] = o;
        }
        __syncthreads();
        const int oc = tid >> 2;                // out-row (E-col), 0..63
        const int cq = tid & 3;
        #pragma unroll
        for (int s = 0; s < 4; ++s){
            const int rr = cq * 4 + s * 16;     // out-col base (C-row)
            ushort4 o = make_ushort4(f2bf(tile[rr    ][oc]), f2bf(tile[rr + 1][oc]),
                                     f2bf(tile[rr + 2][oc]), f2bf(tile[rr + 3][oc]));
            *(ushort4*)&xbTp[(long)(c0 + oc) * Cc + r0 + rr] = o;
        }
    } else {
        const long n0 = (long)Ee * Ee / 4, n1 = n0, n2 = (long)Cc * Cc / 4;
        long i = (long)(blk - 4096) * 256 + tid;
        const long stride = 2048L * 256;
        const long tot = n0 + n1 + n2;
        for (; i < tot; i += stride){
            const float* s; u16* d; long k;
            if (i < n0)          { s = fw; d = fwb; k = i; }
            else if (i < n0 + n1){ s = vw; d = vwb; k = i - n0; }
            else                 { s = aw; d = awb; k = i - n0 - n1; }
            float4 f = ((const float4*)s)[k];
            ((ushort4*)d)[k] = make_ushort4(f2bf(f.x), f2bf(f.y), f2bf(f.z), f2bf(f.w));
        }
    }
}

// ====== 256x256 NT GEMM — R8/R11/R14 K-loop core (proven best: up-front 8-burst staging) ======
// C[m,n] = scale*sum_k A[m,k]B[n,k]; A:[M,K], B:[N,K] bf16 row-major.
// 512 thr = 8 waves (2M x 4N); BK=64; LDS 128KiB double-buffered.
// EPI: 0 plain (+bias, bf16/fp32 store) | 1 exp+row-partials | 2 div-by-rowsum fp32
//      | 3 split-yv: tileN<1024 -> y[c][f]+bias; else vxT[f-1024][c] transposed +bias2.
template<int BIAS_MODE, int OUT_F32, int EPI>
__global__ __launch_bounds__(512, 2)
void k_gemm256(const u16* __restrict__ A, const u16* __restrict__ Bm,
               void* __restrict__ Cout, const float* __restrict__ bias,
               const float* __restrict__ bias2, float* __restrict__ extra,
               int N, int K, long sA, long sB, long sC, float scale)
{
    __shared__ __attribute__((aligned(16))) char smem[131072];

    // ---- bijective XCD swizzle (nwg % 8 == 0 for all launches here)
    const int gx = gridDim.x, gy = gridDim.y;
    const int nwg = gx * gy * gridDim.z;
    const int lin = blockIdx.x + gx * (blockIdx.y + gy * blockIdx.z);
    const int swz = (lin & 7) * (nwg >> 3) + (lin >> 3);
    const int bx = swz % gx;
    const int tmp = swz / gx;
    const int by = tmp % gy;
    const int bz = tmp / gy;

    const u16* Ap  = A  + (long)bz * sA;
    const u16* Bp  = Bm + (long)bz * sB;
    u16*   Cm = (u16*)Cout + (long)bz * sC;
    float* Cf = (float*)Cout + (long)bz * sC;

    const int tid  = threadIdx.x;
    const int lane = tid & 63;
    const int wave = tid >> 6;
    const int wr = wave >> 2;          // 0..1  (M half)
    const int wc = wave & 3;           // 0..3  (N quarter)
    const int tileM = bx * 256;
    const int tileN = by * 256;

    // ---- staging constants: unit = 64 rows x 64 cols (8KiB) = 1 gld16/thread
    const int srow   = tid >> 3;
    const int schunk = (tid & 7) ^ (srow & 7);   // pre-swizzled 16B chunk
    const u16* Ag = Ap + (long)(tileM + srow) * K + schunk * 8;
    const u16* Bg = Bp + (long)(tileN + srow) * K + schunk * 8;
    const long uK = (long)64 * K;
    const int  ldst = tid * 16;

    // ---- ds_read constants (swizzled chunk)
    const int lrow = lane & 15;
    const int lk   = lane >> 4;
    const int sw   = lrow & 7;
    const int cs0  = ((0 + lk) ^ sw) * 16;
    const int cs1  = ((4 + lk) ^ sw) * 16;
    const int arow0 = (wr*128 + lrow) * 128;
    const int brow0 = 32768 + (wc*64 + lrow) * 128;

    f32x4 acc[8][4];
    #pragma unroll
    for (int m = 0; m < 8; ++m)
        #pragma unroll
        for (int n = 0; n < 4; ++n)
            acc[m][n] = (f32x4){0.f,0.f,0.f,0.f};

    char* sm = smem;
    #pragma unroll
    for (int u = 0; u < 4; ++u) gld16(Bg + u*uK, sm + 32768 + u*8192 + ldst);
    #pragma unroll
    for (int u = 0; u < 4; ++u) gld16(Ag + u*uK, sm + u*8192 + ldst);
    __syncthreads();

    const int NT = K >> 6;
    short8 aE[4], aO[4], bE[4], bO[4];

    for (int t = 0; t < NT; ++t){
        const bool pref = (t + 1) < NT;
        char* cbuf = sm + ((t & 1) << 16);
        char* nbuf = sm + (((t + 1) & 1) << 16);
        const u16* Agt = Ag + (long)(t + 1) * 64;
        const u16* Bgt = Bg + (long)(t + 1) * 64;

        // ---- issue next tile's staging up-front (8 loads; land during compute)
        if (pref){
            gld16(Agt + 0*uK, nbuf + 0*8192 + ldst);
            gld16(Agt + 1*uK, nbuf + 1*8192 + ldst);
            gld16(Agt + 2*uK, nbuf + 2*8192 + ldst);
            gld16(Agt + 3*uK, nbuf + 3*8192 + ldst);
            gld16(Bgt + 0*uK, nbuf + 32768 + 0*8192 + ldst);
            gld16(Bgt + 1*uK, nbuf + 32768 + 1*8192 + ldst);
            gld16(Bgt + 2*uK, nbuf + 32768 + 2*8192 + ldst);
            gld16(Bgt + 3*uK, nbuf + 32768 + 3*8192 + ldst);
        }

        // ---- batch1: aE(m0-3,kk0), bE(kk0), aO(m4-7,kk0)  [12 reads]
        #pragma unroll
        for (int m = 0; m < 4; ++m) aE[m] = *(const short8*)(cbuf + arow0 + m*2048 + cs0);
        #pragma unroll
        for (int n = 0; n < 4; ++n) bE[n] = *(const short8*)(cbuf + brow0 + n*2048 + cs0);
        #pragma unroll
        for (int m = 0; m < 4; ++m) aO[m] = *(const short8*)(cbuf + arow0 + (m+4)*2048 + cs0);

        LGKM4(); SCHED0();
        #pragma unroll
        for (int m = 0; m < 4; ++m)              // q0: acc[0-3]
            #pragma unroll
            for (int n = 0; n < 4; ++n)
                acc[m][n] = MFMA(aE[m], bE[n], acc[m][n]);

        // ---- batch2: aE <- (m0-3,kk1), bO(kk1)  [8 reads]
        #pragma unroll
        for (int m = 0; m < 4; ++m) aE[m] = *(const short8*)(cbuf + arow0 + m*2048 + cs1);
        #pragma unroll
        for (int n = 0; n < 4; ++n) bO[n] = *(const short8*)(cbuf + brow0 + n*2048 + cs1);
        LGKM8(); SCHED0();
        #pragma unroll
        for (int m = 0; m < 4; ++m)              // q1: acc[4-7]
            #pragma unroll
            for (int n = 0; n < 4; ++n)
                acc[m+4][n] = MFMA(aO[m], bE[n], acc[m+4][n]);

        // ---- batch3: aO <- (m4-7,kk1)  [4 reads]
        #pragma unroll
        for (int m = 0; m < 4; ++m) aO[m] = *(const short8*)(cbuf + arow0 + (m+4)*2048 + cs1);
        LGKM4(); SCHED0();
        #pragma unroll
        for (int m = 0; m < 4; ++m)              // q2: acc[0-3]
            #pragma unroll
            for (int n = 0; n < 4; ++n)
                acc[m][n] = MFMA(aE[m], bO[n], acc[m][n]);

        LGKM0(); SCHED0();
        #pragma unroll
        for (int m = 0; m < 4; ++m)              // q3: acc[4-7]
            #pragma unroll
            for (int n = 0; n < 4; ++n)
                acc[m+4][n] = MFMA(aO[m], bO[n], acc[m+4][n]);

        VMCNT0(); SBAR(); SCHED0();
    }

    // ---- epilogue: C/D layout col=lane&15, row=(lane>>4)*4+j
    const int r0base = tileM + wr*128 + lk*4;
    const int cbase  = tileN + wc*64 + lrow;

    if (EPI == 0){
        #pragma unroll
        for (int m = 0; m < 8; ++m){
            const int r0 = r0base + m*16;
            #pragma unroll
            for (int n = 0; n < 4; ++n){
                const int c = cbase + n*16;
                f32x4 v = acc[m][n];
                #pragma unroll
                for (int j = 0; j < 4; ++j){
                    float val = v[j] * scale;
                    if (BIAS_MODE == 1) val += bias[c];
                    if (BIAS_MODE == 2) val += bias[r0 + j];
                    if (OUT_F32) Cf[(long)(r0 + j) * N + c] = val;
                    else         Cm[(long)(r0 + j) * N + c] = f2bf(val);
                }
            }
        }
    } else if (EPI == 1){
        // store exp(s*scale) bf16; per-row partial sums -> extra[bz][row][by]
        float* lsum = (float*)smem;              // [256 rows][4 wc]
        const int rl0 = wr*128 + lk*4;
        #pragma unroll
        for (int m = 0; m < 8; ++m){
            const int r0 = r0base + m*16;
            #pragma unroll
            for (int j = 0; j < 4; ++j){
                float rp = 0.f;
                #pragma unroll
                for (int n = 0; n < 4; ++n){
                    float e = __expf(acc[m][n][j] * scale);
                    rp += e;
                    Cm[(long)(r0 + j) * N + (cbase + n*16)] = f2bf(e);
                }
                rp += __shfl_xor(rp, 1);
                rp += __shfl_xor(rp, 2);
                rp += __shfl_xor(rp, 4);
                rp += __shfl_xor(rp, 8);
                if (lrow == 0)
                    lsum[(rl0 + m*16 + j)*4 + wc] = rp;
            }
        }
        __syncthreads();
        if (tid < 256){
            float4 v4 = ((const float4*)lsum)[tid];
            extra[((long)bz*Cc + tileM + tid)*8 + by] = v4.x + v4.y + v4.z + v4.w;
        }
    } else if (EPI == 2){
        // divide by row sum (8 partials), fp32 out
        #pragma unroll
        for (int m = 0; m < 8; ++m){
            const int r0 = r0base + m*16;
            #pragma unroll
            for (int j = 0; j < 4; ++j){
                const float4* pr = (const float4*)(extra + ((long)bz*Cc + r0 + j)*8);
                float4 pa = pr[0], pb = pr[1];
                float Ssum = pa.x+pa.y+pa.z+pa.w + pb.x+pb.y+pb.z+pb.w;
                const float inv = 1.f / Ssum;
                #pragma unroll
                for (int n = 0; n < 4; ++n)
                    Cf[(long)(r0 + j) * N + (cbase + n*16)] = acc[m][n][j] * inv;
            }
        }
    } else {
        // EPI == 3: yv split. tileN<1024 -> y half (ld=Ee, +bias[c]);
        //           else vxT[f'][k] transposed (ld=Cc, +bias2[f']), f'=c-1024.
        if (tileN < 1024){
            #pragma unroll
            for (int m = 0; m < 8; ++m){
                const int r0 = r0base + m*16;
                #pragma unroll
                for (int n = 0; n < 4; ++n){
                    const int c = cbase + n*16;
                    f32x4 v = acc[m][n];
                    #pragma unroll
                    for (int j = 0; j < 4; ++j)
                        Cm[(long)(r0 + j) * Ee + c] = f2bf(v[j] + bias[c]);
                }
            }
        } else {
            u16* vxp = (u16*)extra + (long)bz * sC;   // vxT base for this batch
            #pragma unroll
            for (int m = 0; m < 8; ++m){
                const int r0 = r0base + m*16;
                #pragma unroll
                for (int n = 0; n < 4; ++n){
                    const int c = cbase + n*16;
                    const float b2 = bias2[c - 1024];
                    f32x4 v = acc[m][n];
                    ushort4 o = make_ushort4(f2bf(v[0]+b2), f2bf(v[1]+b2),
                                             f2bf(v[2]+b2), f2bf(v[3]+b2));
                    *(ushort4*)&vxp[(long)(c - 1024) * Cc + r0] = o;  // 4 rows contiguous
                }
            }
        }
    }
}

extern "C" void kernel_launch(void* const* d_in, const int* in_sizes, int n_in,
                              void* d_out, int out_size, void* d_ws, size_t ws_size,
                              hipStream_t stream)
{
    const float* x     = (const float*)d_in[0];
    const float* fc_w  = (const float*)d_in[1];
    const float* fc_b  = (const float*)d_in[2];
    const float* altw  = (const float*)d_in[3];
    const float* altb  = (const float*)d_in[4];
    const float* vfc_w = (const float*)d_in[5];
    const float* vfc_b = (const float*)d_in[6];
    float* out = (float*)d_out;   // reference output is fp32

    char* ws = (char*)d_ws;
    const size_t nBCE = (size_t)Bb * Cc * Ee;            // 16,777,216 elements
    u16* xb   = (u16*)(ws);                              // [B][C][E]
    u16* xbT  = (u16*)(ws + 2 * nBCE);                   // [B][E][C]
    u16* P    = (u16*)(ws);                              // [B][C][C] (aliases xb+xbT; written only
                                                         //   after all xb/xbT readers complete)
    u16* y    = (u16*)(ws + 4 * nBCE);                   // [B][C][E]
    u16* z    = (u16*)(ws + 6 * nBCE);                   // [B][C][E]   z[b][k][e] = yx[b,e,k]
    u16* vxT  = (u16*)(ws + 8 * nBCE);                   // [B][E][C]   vxT[b][f][k] = vx[b,k,f]
    u16* fcwb = (u16*)(ws + 10 * nBCE);                  // [E][E]  } contiguous => 2048x1024
    u16* vfwb = fcwb + (size_t)Ee * Ee;                  // [E][E]  } concatenated weight wcat
    u16* awb  = vfwb + (size_t)Ee * Ee;                  // [C][C]
    float* rpart = (float*)(ws + 10 * nBCE + 2*((size_t)Ee*Ee*2 + (size_t)Cc*Cc));  // after weights

    const long sBCE = (long)Cc * Ee;
    const long sBCC = (long)Cc * Cc;
    dim3 blk(512);

    // 1) merged prep: x cast(+transpose, vectorized) + 3 weight casts
    k_prep<<<6144, 256, 0, stream>>>(x, xb, xbT, fc_w, fcwb, vfc_w, vfwb, altw, awb);

    // 2) z[b][k][e] = sum_c altw[k,c] xT[e,c] + alt_b[k]      M=C,N=E,K=C (bias row)
    k_gemm256<2, 0, 0><<<dim3(8, 4, Bb), blk, 0, stream>>>(
        awb, xbT, z, altb, nullptr, nullptr, Ee, Cc, 0, sBCE, sBCE, 1.f);

    // 3) yv combined: A=xb, B=wcat(2048x1024). f<1024 -> y[c][f]+fc_b; f>=1024 ->
    //    vxT[f-1024][c]+vfc_b (transposed store).  M=C, N=2048, K=E.
    k_gemm256<0, 0, 3><<<dim3(8, 8, Bb), blk, 0, stream>>>(
        xb, fcwb, y, fc_b, vfc_b, (float*)vxT, 2048, Ee, sBCE, 0, sBCE, 1.f);

    // 4) Pexp[b][c][k] = exp(scale * sum_e y[c,e] z[k,e]); row partials -> rpart
    k_gemm256<0, 0, 1><<<dim3(8, 8, Bb), blk, 0, stream>>>(
        y, z, P, nullptr, nullptr, rpart, Cc, Ee, sBCE, sBCE, sBCC, 0.022097086912079608f);

    // 5) out[b][c][e] = (sum_k Pexp[c,k] vxT[e,k]) / rowsum[c] -> fp32
    k_gemm256<0, 1, 2><<<dim3(8, 4, Bb), blk, 0, stream>>>(
        P, vxT, out, nullptr, nullptr, rpart, Ee, Cc, sBCC, sBCE, sBCE, 1.f);
}